// Round 9
// baseline (131.398 us; speedup 1.0000x reference)
//
#include <hip/hip_runtime.h>
#include <hip/hip_bf16.h>
#include <cstdint>

#define DEV static __device__ __forceinline__

typedef unsigned short u16t;
typedef __attribute__((ext_vector_type(4))) float f32x4;
typedef __attribute__((ext_vector_type(4))) unsigned short u16x4;
typedef __attribute__((ext_vector_type(8))) unsigned short u16x8;
typedef __attribute__((ext_vector_type(8))) __bf16 bf16x8;

DEV u16t f2bf(float f) {
  unsigned u = __builtin_bit_cast(unsigned, f);
  u += 0x7fffu + ((u >> 16) & 1u);
  return (u16t)(u >> 16);
}
DEV float bf2f(u16t h) {
  unsigned u = ((unsigned)h) << 16;
  return __builtin_bit_cast(float, u);
}

DEV void gload_lds16(const void* g, void* l) {
  __builtin_amdgcn_global_load_lds(
      (const __attribute__((address_space(1))) void*)g,
      (__attribute__((address_space(3))) void*)l, 16, 0, 0);
}

DEV bf16x8 ldsfrag(const u16t* p) {
  return __builtin_bit_cast(bf16x8, *(const u16x8*)p);
}

// raw workgroup barrier WITHOUT __syncthreads' implicit vmcnt(0) drain
DEV void bsync() {
  asm volatile("" ::: "memory");
  __builtin_amdgcn_s_barrier();
  asm volatile("" ::: "memory");
}

// ---------------- convert x (fp32 -> bf16) ----------------
__global__ __launch_bounds__(256) void k_convert_x(const float* __restrict__ x,
                                                   u16t* __restrict__ xb) {
  int i = (blockIdx.x * 256 + threadIdx.x) * 4;
  f32x4 v = *(const f32x4*)&x[i];
  u16x4 o;
#pragma unroll
  for (int j = 0; j < 4; ++j) o[j] = f2bf(v[j]);
  *(u16x4*)&xb[i] = o;
}

// ------------- transpose + convert weights (fp32 [K][N] -> bf16 [N][K]) -------------
__global__ __launch_bounds__(256) void k_transw(const float* __restrict__ w0,
                                                const float* __restrict__ w1,
                                                const float* __restrict__ w2,
                                                const float* __restrict__ w3,
                                                u16t* __restrict__ qkvT,
                                                u16t* __restrict__ oT) {
  __shared__ float lds[64][68];
  int z = blockIdx.z;
  const float* W = (z == 0) ? w0 : (z == 1) ? w1 : (z == 2) ? w2 : w3;
  u16t* OUT = (z < 3) ? (qkvT + (size_t)z * 1024 * 1024) : oT;
  int k0 = blockIdx.x * 64, n0 = blockIdx.y * 64;
  int t = threadIdx.x;
  int kl = t >> 4, n4 = (t & 15) << 2;
#pragma unroll
  for (int p = 0; p < 4; ++p) {
    f32x4 v = *(const f32x4*)&W[(size_t)(k0 + kl + p * 16) * 1024 + n0 + n4];
    *(f32x4*)&lds[kl + p * 16][n4] = v;
  }
  __syncthreads();
  int nl = t >> 4, k4 = (t & 15) << 2;
#pragma unroll
  for (int p = 0; p < 4; ++p) {
    int n = nl + p * 16;
    u16x4 o;
#pragma unroll
    for (int i = 0; i < 4; ++i) o[i] = f2bf(lds[k4 + i][n]);
    *(u16x4*)&OUT[(size_t)(n0 + n) * 1024 + k0 + k4] = o;
  }
}

// ---------------- GEMM: C[M,N] = A[M,K] * BT[N,K]^T + bias ----------------
// 2-phase counted-vmcnt double-buffer (r7-proven).
// VSPLIT: cols >= 2048 (the V projection) are written transposed into vt[bh][d][s].
template <bool BF16_OUT, bool VSPLIT>
__global__ __launch_bounds__(256) void k_gemm_bt(const u16t* __restrict__ A,
                                                 const u16t* __restrict__ BT,
                                                 void* __restrict__ Cout,
                                                 const float* __restrict__ b0,
                                                 const float* __restrict__ b1,
                                                 const float* __restrict__ b2,
                                                 u16t* __restrict__ vt,
                                                 int M, int N, int K) {
  __shared__ u16t Al[2][128 * 64];
  __shared__ u16t Bl[2][128 * 64];
  const int tid = threadIdx.x;
  const int l = tid & 63;
  const int w = tid >> 6;
  const int m0 = blockIdx.x * 128, n0 = blockIdx.y * 128;
  const int wm = (w >> 1) * 64, wn = (w & 1) * 64;
  const int lm = l & 15, lh = l >> 4;
  f32x4 acc[4][4] = {};

  auto stage = [&](int bb, int t) {
    const int k0 = t << 6;
#pragma unroll
    for (int s = 0; s < 4; ++s) {
      int c = s * 256 + tid;
      int row = c >> 3, slot = c & 7;
      int ks = k0 + (((slot ^ (row & 7)) & 7) << 3);
      gload_lds16(A + (size_t)(m0 + row) * K + ks, &Al[bb][c * 8]);
    }
#pragma unroll
    for (int s = 0; s < 4; ++s) {
      int c = s * 256 + tid;
      int row = c >> 3, slot = c & 7;
      int ks = k0 + (((slot ^ (row & 7)) & 7) << 3);
      gload_lds16(BT + (size_t)(n0 + row) * K + ks, &Bl[bb][c * 8]);
    }
  };

  const int nt = K >> 6;
  stage(0, 0);
  for (int t = 0; t < nt; ++t) {
    if (t + 1 < nt) {
      stage((t + 1) & 1, t + 1);
      asm volatile("s_waitcnt vmcnt(8)" ::: "memory");
    } else {
      asm volatile("s_waitcnt vmcnt(0)" ::: "memory");
    }
    bsync();
    const int buf = t & 1;

#pragma unroll
    for (int kk = 0; kk < 2; ++kk) {
      bf16x8 af[4], bfr[4];
#pragma unroll
      for (int i = 0; i < 4; ++i) {
        int ra = wm + i * 16 + lm;
        int sa = (kk * 4 + lh) ^ (ra & 7);
        af[i] = ldsfrag(&Al[buf][ra * 64 + sa * 8]);
        int rb = wn + i * 16 + lm;
        int sb = (kk * 4 + lh) ^ (rb & 7);
        bfr[i] = ldsfrag(&Bl[buf][rb * 64 + sb * 8]);
      }
#pragma unroll
      for (int i = 0; i < 4; ++i)
#pragma unroll
        for (int j = 0; j < 4; ++j)
          acc[i][j] = __builtin_amdgcn_mfma_f32_16x16x32_bf16(af[i], bfr[j],
                                                              acc[i][j], 0, 0, 0);
    }
    bsync();
  }

  if (!VSPLIT || (n0 + wn) < 2048) {
#pragma unroll
    for (int i = 0; i < 4; ++i) {
      int row = m0 + wm + i * 16 + (lh << 2);
#pragma unroll
      for (int j = 0; j < 4; ++j) {
        int col = n0 + wn + j * 16 + lm;
        const float* bp = (col < 1024) ? b0 : ((col < 2048) ? b1 : b2);
        float bias = bp[col & 1023];
#pragma unroll
        for (int r = 0; r < 4; ++r) {
          float v = acc[i][j][r] + bias;
          if (BF16_OUT)
            ((u16t*)Cout)[(size_t)(row + r) * N + col] = f2bf(v);
          else
            ((float*)Cout)[(size_t)(row + r) * N + col] = v;
        }
      }
    }
  } else {
    // V projection: write transposed to vt[(b*16+h)*64 + d][s]
#pragma unroll
    for (int i = 0; i < 4; ++i) {
      int row = m0 + wm + i * 16 + (lh << 2);
      int bidx = row >> 11, s0 = row & 2047;
#pragma unroll
    for (int j = 0; j < 4; ++j) {
        int col = n0 + wn + j * 16 + lm;
        int d = col - 2048;
        int hh = d >> 6, dd = d & 63;
        float bias = b2[d];
        u16x4 o;
#pragma unroll
        for (int r = 0; r < 4; ++r) o[r] = f2bf(acc[i][j][r] + bias);
        *(u16x4*)&vt[((size_t)((bidx * 16 + hh) * 64 + dd)) * 2048 + s0] = o;
      }
    }
  }
}

// ---------------- causal flash attention ----------------
// 64-row q-tiles (r6/r7 concurrency regime: 1024 blocks, 40KB LDS, 4 blocks/CU)
// but 128-thread blocks = 2 waves x 32 q-rows (r8-proven 2-fragment inner loop):
// K/V LDS re-reads halved vs r7. r6-proven y->qt bijection pairs co-resident
// blocks (qt(y)+qt(y+8)=31). Softmax in exp2 domain (log2e folded into Q scale).
__global__ __launch_bounds__(128, 2) void k_attn(const u16t* __restrict__ qkv,
                                                 const u16t* __restrict__ vt,
                                                 u16t* __restrict__ outp) {
  __shared__ u16t Kl[2][4096];     // [kv=64][d=64], 16B-slot swizzled
  __shared__ u16t Vl[2][4096];     // [d=64][kv=64], 16B-slot swizzled
  __shared__ u16t Pl[2][2][1024];  // [wave][qm][q=16][kv=64], swizzled
  const int tid = threadIdx.x, l = tid & 63, w = tid >> 6;
  const int lm = l & 15, lh = l >> 4;
  const int bh = blockIdx.x, b = bh >> 4, h = bh & 15;
  const int y = blockIdx.y;
  const int qt = (y < 8) ? y : (y < 16) ? (39 - y) : (y < 24) ? (y - 8) : (47 - y);
  const int q0 = qt * 64;
  const int nt = qt + 1;
  const int qbase = q0 + w * 32;

  const u16t* Kg = qkv + (size_t)b * 2048 * 3072 + 1024 + h * 64;
  const u16t* Vg = vt + (size_t)bh * 64 * 2048;

  // Q fragments (B-operand), pre-scaled by (1/sqrt(64))*log2(e) -> exp2 softmax
  bf16x8 aq[2][2];
#pragma unroll
  for (int qm = 0; qm < 2; ++qm)
#pragma unroll
    for (int kk = 0; kk < 2; ++kk) {
      const u16t* src = qkv + (size_t)(b * 2048 + qbase + qm * 16 + lm) * 3072 +
                        h * 64 + kk * 32 + lh * 8;
      u16x8 v = *(const u16x8*)src;
      u16x8 o;
#pragma unroll
      for (int e = 0; e < 8; ++e) o[e] = f2bf(bf2f(v[e]) * 0.1803368801f);
      aq[qm][kk] = __builtin_bit_cast(bf16x8, o);
    }

  float mrun[2] = {-1e30f, -1e30f};
  float lsum[2] = {0.f, 0.f};
  f32x4 aco[2][4] = {};
  const int qr0 = qbase + lm, qr1 = qbase + 16 + lm;

  auto stage = [&](int bb, int t) {
#pragma unroll
    for (int s = 0; s < 4; ++s) {
      int c = s * 128 + tid;
      int row = c >> 3, col = ((c & 7) ^ (row & 7)) << 3;
      gload_lds16(Kg + (size_t)(t * 64 + row) * 3072 + col, &Kl[bb][c * 8]);
    }
#pragma unroll
    for (int s = 0; s < 4; ++s) {
      int c = s * 128 + tid;
      int row = c >> 3, col = ((c & 7) ^ (row & 7)) << 3;
      gload_lds16(Vg + (size_t)row * 2048 + t * 64 + col, &Vl[bb][c * 8]);
    }
  };

  stage(0, 0);

  int buf = 0;
  for (int t = 0; t < nt; ++t) {
    if (t + 1 < nt) {
      stage(buf ^ 1, t + 1);
      asm volatile("s_waitcnt vmcnt(8)" ::: "memory");
    } else {
      asm volatile("s_waitcnt vmcnt(0)" ::: "memory");
    }
    bsync();

    // S^T = K * Q
    f32x4 accs[2][4] = {};
#pragma unroll
    for (int kk = 0; kk < 2; ++kk) {
      bf16x8 ak[4];
#pragma unroll
      for (int nk = 0; nk < 4; ++nk) {
        int rk = nk * 16 + lm;
        int s16 = (kk * 4 + lh) ^ (rk & 7);
        ak[nk] = ldsfrag(&Kl[buf][rk * 64 + s16 * 8]);
      }
      __builtin_amdgcn_s_setprio(1);
#pragma unroll
      for (int nk = 0; nk < 4; ++nk) {
        accs[0][nk] = __builtin_amdgcn_mfma_f32_16x16x32_bf16(ak[nk], aq[0][kk],
                                                              accs[0][nk], 0, 0, 0);
        accs[1][nk] = __builtin_amdgcn_mfma_f32_16x16x32_bf16(ak[nk], aq[1][kk],
                                                              accs[1][nk], 0, 0, 0);
      }
      __builtin_amdgcn_s_setprio(0);
    }

    // tile max; causal mask only on the diagonal tile (t == nt-1, block-uniform)
    float vmax[2] = {-1e30f, -1e30f};
    if (t == nt - 1) {
#pragma unroll
      for (int nk = 0; nk < 4; ++nk)
#pragma unroll
        for (int r = 0; r < 4; ++r) {
          int kvpos = t * 64 + nk * 16 + lh * 4 + r;
          float v0 = accs[0][nk][r];
          v0 = (kvpos > qr0) ? -1e30f : v0;
          accs[0][nk][r] = v0;
          vmax[0] = fmaxf(vmax[0], v0);
          float v1 = accs[1][nk][r];
          v1 = (kvpos > qr1) ? -1e30f : v1;
          accs[1][nk][r] = v1;
          vmax[1] = fmaxf(vmax[1], v1);
        }
    } else {
#pragma unroll
      for (int nk = 0; nk < 4; ++nk)
#pragma unroll
        for (int r = 0; r < 4; ++r) {
          vmax[0] = fmaxf(vmax[0], accs[0][nk][r]);
          vmax[1] = fmaxf(vmax[1], accs[1][nk][r]);
        }
    }

    // defer-max (exp2 domain): rescale only when tile max exceeds running max by >8
    if (!__all((vmax[0] <= mrun[0] + 8.f) & (vmax[1] <= mrun[1] + 8.f))) {
#pragma unroll
      for (int qm = 0; qm < 2; ++qm) {
        float rm = fmaxf(vmax[qm], __shfl_xor(vmax[qm], 16));
        rm = fmaxf(rm, __shfl_xor(rm, 32));
        float mnew = fmaxf(mrun[qm], rm);
        float alpha = exp2f(mrun[qm] - mnew);
        mrun[qm] = mnew;
        lsum[qm] *= alpha;
#pragma unroll
        for (int r = 0; r < 4; ++r) {
          float ar = __shfl(alpha, lh * 4 + r);
#pragma unroll
          for (int nd = 0; nd < 4; ++nd) aco[qm][nd][r] *= ar;
        }
      }
    }

    // p = exp2(s - mrun), pack via v_cvt_pk_bf16_f32, b64 store to P-LDS
#pragma unroll
    for (int qm = 0; qm < 2; ++qm) {
      u16t* Pw = &Pl[w][qm][0];
#pragma unroll
      for (int nk = 0; nk < 4; ++nk) {
        float p0 = exp2f(accs[qm][nk][0] - mrun[qm]);
        float p1 = exp2f(accs[qm][nk][1] - mrun[qm]);
        float p2 = exp2f(accs[qm][nk][2] - mrun[qm]);
        float p3 = exp2f(accs[qm][nk][3] - mrun[qm]);
        lsum[qm] += (p0 + p1) + (p2 + p3);
        unsigned wlo, whi;
        asm("v_cvt_pk_bf16_f32 %0, %1, %2" : "=v"(wlo) : "v"(p0), "v"(p1));
        asm("v_cvt_pk_bf16_f32 %0, %1, %2" : "=v"(whi) : "v"(p2), "v"(p3));
        int off = lm * 64 + ((((2 * nk + (lh >> 1)) ^ (lm & 7)) & 7) << 3) +
                  ((lh & 1) << 2);
        *(uint2*)&Pw[off] = make_uint2(wlo, whi);
      }
    }

    // O += P * V
#pragma unroll
    for (int kk = 0; kk < 2; ++kk) {
      int sp = (kk * 4 + lh) ^ (lm & 7);
      bf16x8 ap0 = ldsfrag(&Pl[w][0][lm * 64 + sp * 8]);
      bf16x8 ap1 = ldsfrag(&Pl[w][1][lm * 64 + sp * 8]);
      __builtin_amdgcn_s_setprio(1);
#pragma unroll
      for (int nd = 0; nd < 4; ++nd) {
        int rv = nd * 16 + lm;
        int sv = (kk * 4 + lh) ^ (rv & 7);
        bf16x8 bv = ldsfrag(&Vl[buf][rv * 64 + sv * 8]);
        aco[0][nd] =
            __builtin_amdgcn_mfma_f32_16x16x32_bf16(ap0, bv, aco[0][nd], 0, 0, 0);
        aco[1][nd] =
            __builtin_amdgcn_mfma_f32_16x16x32_bf16(ap1, bv, aco[1][nd], 0, 0, 0);
      }
      __builtin_amdgcn_s_setprio(0);
    }

    bsync();
    buf ^= 1;
  }

  // epilogue: reduce lsum over lane-groups, normalize, store
#pragma unroll
  for (int qm = 0; qm < 2; ++qm) {
    float ls = lsum[qm];
    ls += __shfl_xor(ls, 16);
    ls += __shfl_xor(ls, 32);
    float inv = 1.0f / ls;
#pragma unroll
    for (int r = 0; r < 4; ++r) {
      float ir = __shfl(inv, lh * 4 + r);
      int row = qbase + qm * 16 + lh * 4 + r;
#pragma unroll
      for (int nd = 0; nd < 4; ++nd) {
        int col = h * 64 + nd * 16 + lm;
        outp[(size_t)(b * 2048 + row) * 1024 + col] = f2bf(aco[qm][nd][r] * ir);
      }
    }
  }
}

extern "C" void kernel_launch(void* const* d_in, const int* in_sizes, int n_in,
                              void* d_out, int out_size, void* d_ws, size_t ws_size,
                              hipStream_t stream) {
  const float* x = (const float*)d_in[0];
  const float* wq = (const float*)d_in[1];
  const float* bq = (const float*)d_in[2];
  const float* wk = (const float*)d_in[3];
  const float* bk = (const float*)d_in[4];
  const float* wv = (const float*)d_in[5];
  const float* bv = (const float*)d_in[6];
  const float* wo = (const float*)d_in[7];
  const float* bo = (const float*)d_in[8];

  char* ws = (char*)d_ws;
  u16t* xb = (u16t*)ws;                    //  8 MB: x bf16 (later reused as attn_out)
  u16t* wqkvT = (u16t*)(ws + (8u << 20));  //  6 MB: [wq^T; wk^T; wv^T] bf16
  u16t* woT = (u16t*)(ws + (14u << 20));   //  2 MB: wo^T bf16
  u16t* qkv = (u16t*)(ws + (16u << 20));   // 24 MB: [4096][3072] bf16 (V third unused)
  u16t* vt = (u16t*)(ws + (40u << 20));    //  8 MB: [32][64][2048] bf16
  u16t* attn_out = xb;

  k_convert_x<<<4096, 256, 0, stream>>>(x, xb);
  k_transw<<<dim3(16, 16, 4), 256, 0, stream>>>(wq, wk, wv, wo, wqkvT, woT);
  k_gemm_bt<true, true><<<dim3(32, 24), 256, 0, stream>>>(xb, wqkvT, qkv, bq, bk,
                                                          bv, vt, 4096, 3072, 1024);
  k_attn<<<dim3(32, 32), 128, 0, stream>>>(qkv, vt, attn_out);
  k_gemm_bt<false, false><<<dim3(32, 8), 256, 0, stream>>>(
      attn_out, woT, d_out, bo, bo, bo, nullptr, 4096, 1024, 1024);
}

// Round 10
// 112.299 us; speedup vs baseline: 1.1701x; 1.1701x over previous
//
#include <hip/hip_runtime.h>
#include <hip/hip_bf16.h>
#include <cstdint>

#define DEV static __device__ __forceinline__

typedef unsigned short u16t;
typedef __attribute__((ext_vector_type(4))) float f32x4;
typedef __attribute__((ext_vector_type(4))) unsigned short u16x4;
typedef __attribute__((ext_vector_type(8))) unsigned short u16x8;
typedef __attribute__((ext_vector_type(8))) __bf16 bf16x8;

DEV u16t f2bf(float f) {
  unsigned u = __builtin_bit_cast(unsigned, f);
  u += 0x7fffu + ((u >> 16) & 1u);
  return (u16t)(u >> 16);
}
DEV float bf2f(u16t h) {
  unsigned u = ((unsigned)h) << 16;
  return __builtin_bit_cast(float, u);
}

DEV void gload_lds16(const void* g, void* l) {
  __builtin_amdgcn_global_load_lds(
      (const __attribute__((address_space(1))) void*)g,
      (__attribute__((address_space(3))) void*)l, 16, 0, 0);
}

DEV bf16x8 ldsfrag(const u16t* p) {
  return __builtin_bit_cast(bf16x8, *(const u16x8*)p);
}

// raw workgroup barrier WITHOUT __syncthreads' implicit vmcnt(0) drain
DEV void bsync() {
  asm volatile("" ::: "memory");
  __builtin_amdgcn_s_barrier();
  asm volatile("" ::: "memory");
}

// ---------------- convert x (fp32 -> bf16) ----------------
__global__ __launch_bounds__(256) void k_convert_x(const float* __restrict__ x,
                                                   u16t* __restrict__ xb) {
  int i = (blockIdx.x * 256 + threadIdx.x) * 4;
  f32x4 v = *(const f32x4*)&x[i];
  u16x4 o;
#pragma unroll
  for (int j = 0; j < 4; ++j) o[j] = f2bf(v[j]);
  *(u16x4*)&xb[i] = o;
}

// ------------- transpose + convert weights (fp32 [K][N] -> bf16 [N][K]) -------------
__global__ __launch_bounds__(256) void k_transw(const float* __restrict__ w0,
                                                const float* __restrict__ w1,
                                                const float* __restrict__ w2,
                                                const float* __restrict__ w3,
                                                u16t* __restrict__ qkvT,
                                                u16t* __restrict__ oT) {
  __shared__ float lds[64][68];
  int z = blockIdx.z;
  const float* W = (z == 0) ? w0 : (z == 1) ? w1 : (z == 2) ? w2 : w3;
  u16t* OUT = (z < 3) ? (qkvT + (size_t)z * 1024 * 1024) : oT;
  int k0 = blockIdx.x * 64, n0 = blockIdx.y * 64;
  int t = threadIdx.x;
  int kl = t >> 4, n4 = (t & 15) << 2;
#pragma unroll
  for (int p = 0; p < 4; ++p) {
    f32x4 v = *(const f32x4*)&W[(size_t)(k0 + kl + p * 16) * 1024 + n0 + n4];
    *(f32x4*)&lds[kl + p * 16][n4] = v;
  }
  __syncthreads();
  int nl = t >> 4, k4 = (t & 15) << 2;
#pragma unroll
  for (int p = 0; p < 4; ++p) {
    int n = nl + p * 16;
    u16x4 o;
#pragma unroll
    for (int i = 0; i < 4; ++i) o[i] = f2bf(lds[k4 + i][n]);
    *(u16x4*)&OUT[(size_t)(n0 + n) * 1024 + k0 + k4] = o;
  }
}

// ---------------- GEMM: C[M,N] = A[M,K] * BT[N,K]^T + bias ----------------
// 2-phase counted-vmcnt double-buffer (r7-proven).
// VSPLIT: cols >= 2048 (the V projection) are written transposed into vt[bh][d][s].
template <bool BF16_OUT, bool VSPLIT>
__global__ __launch_bounds__(256) void k_gemm_bt(const u16t* __restrict__ A,
                                                 const u16t* __restrict__ BT,
                                                 void* __restrict__ Cout,
                                                 const float* __restrict__ b0,
                                                 const float* __restrict__ b1,
                                                 const float* __restrict__ b2,
                                                 u16t* __restrict__ vt,
                                                 int M, int N, int K) {
  __shared__ u16t Al[2][128 * 64];
  __shared__ u16t Bl[2][128 * 64];
  const int tid = threadIdx.x;
  const int l = tid & 63;
  const int w = tid >> 6;
  const int m0 = blockIdx.x * 128, n0 = blockIdx.y * 128;
  const int wm = (w >> 1) * 64, wn = (w & 1) * 64;
  const int lm = l & 15, lh = l >> 4;
  f32x4 acc[4][4] = {};

  auto stage = [&](int bb, int t) {
    const int k0 = t << 6;
#pragma unroll
    for (int s = 0; s < 4; ++s) {
      int c = s * 256 + tid;
      int row = c >> 3, slot = c & 7;
      int ks = k0 + (((slot ^ (row & 7)) & 7) << 3);
      gload_lds16(A + (size_t)(m0 + row) * K + ks, &Al[bb][c * 8]);
    }
#pragma unroll
    for (int s = 0; s < 4; ++s) {
      int c = s * 256 + tid;
      int row = c >> 3, slot = c & 7;
      int ks = k0 + (((slot ^ (row & 7)) & 7) << 3);
      gload_lds16(BT + (size_t)(n0 + row) * K + ks, &Bl[bb][c * 8]);
    }
  };

  const int nt = K >> 6;
  stage(0, 0);
  for (int t = 0; t < nt; ++t) {
    if (t + 1 < nt) {
      stage((t + 1) & 1, t + 1);
      asm volatile("s_waitcnt vmcnt(8)" ::: "memory");
    } else {
      asm volatile("s_waitcnt vmcnt(0)" ::: "memory");
    }
    bsync();
    const int buf = t & 1;

#pragma unroll
    for (int kk = 0; kk < 2; ++kk) {
      bf16x8 af[4], bfr[4];
#pragma unroll
      for (int i = 0; i < 4; ++i) {
        int ra = wm + i * 16 + lm;
        int sa = (kk * 4 + lh) ^ (ra & 7);
        af[i] = ldsfrag(&Al[buf][ra * 64 + sa * 8]);
        int rb = wn + i * 16 + lm;
        int sb = (kk * 4 + lh) ^ (rb & 7);
        bfr[i] = ldsfrag(&Bl[buf][rb * 64 + sb * 8]);
      }
#pragma unroll
      for (int i = 0; i < 4; ++i)
#pragma unroll
        for (int j = 0; j < 4; ++j)
          acc[i][j] = __builtin_amdgcn_mfma_f32_16x16x32_bf16(af[i], bfr[j],
                                                              acc[i][j], 0, 0, 0);
    }
    bsync();
  }

  if (!VSPLIT || (n0 + wn) < 2048) {
#pragma unroll
    for (int i = 0; i < 4; ++i) {
      int row = m0 + wm + i * 16 + (lh << 2);
#pragma unroll
      for (int j = 0; j < 4; ++j) {
        int col = n0 + wn + j * 16 + lm;
        const float* bp = (col < 1024) ? b0 : ((col < 2048) ? b1 : b2);
        float bias = bp[col & 1023];
#pragma unroll
        for (int r = 0; r < 4; ++r) {
          float v = acc[i][j][r] + bias;
          if (BF16_OUT)
            ((u16t*)Cout)[(size_t)(row + r) * N + col] = f2bf(v);
          else
            ((float*)Cout)[(size_t)(row + r) * N + col] = v;
        }
      }
    }
  } else {
    // V projection: write transposed to vt[(b*16+h)*64 + d][s]
#pragma unroll
    for (int i = 0; i < 4; ++i) {
      int row = m0 + wm + i * 16 + (lh << 2);
      int bidx = row >> 11, s0 = row & 2047;
#pragma unroll
    for (int j = 0; j < 4; ++j) {
        int col = n0 + wn + j * 16 + lm;
        int d = col - 2048;
        int hh = d >> 6, dd = d & 63;
        float bias = b2[d];
        u16x4 o;
#pragma unroll
        for (int r = 0; r < 4; ++r) o[r] = f2bf(acc[i][j][r] + bias);
        *(u16x4*)&vt[((size_t)((bidx * 16 + hh) * 64 + dd)) * 2048 + s0] = o;
      }
    }
  }
}

// ---------------- causal flash attention ----------------
// r7-proven kernel with SINGLE-buffered K/V (LDS 40KB -> 24KB): under the
// measured ~80-96KB effective LDS pool this raises co-resident blocks/CU from
// 2 to 3-4, trading intra-block prefetch for inter-block TLP. Schedule per
// iter: stage(t) -> vmcnt(0) -> barrier -> compute -> barrier (r1-proven shape).
// grid: (B*H=32, 32 q-tiles of 64 rows), 4 waves x 16 q-rows; y->qt bijection
// pairs co-resident blocks (qt(y)+qt(y+8)=31).
__global__ __launch_bounds__(256, 4) void k_attn(const u16t* __restrict__ qkv,
                                                 const u16t* __restrict__ vt,
                                                 u16t* __restrict__ outp) {
  __shared__ u16t Kl[4096];     // [kv=64][d=64], 16B-slot swizzled
  __shared__ u16t Vl[4096];     // [d=64][kv=64], 16B-slot swizzled
  __shared__ u16t Pl[4][1024];  // per-wave P [q=16][kv=64], swizzled
  const int tid = threadIdx.x, l = tid & 63, w = tid >> 6;
  const int lm = l & 15, lh = l >> 4;
  const int bh = blockIdx.x, b = bh >> 4, h = bh & 15;
  const int y = blockIdx.y;
  const int qt = (y < 8) ? y : (y < 16) ? (39 - y) : (y < 24) ? (y - 8) : (47 - y);
  const int q0 = qt * 64;
  const int nt = qt + 1;

  // Q fragment (B-operand layout), pre-scaled by 1/sqrt(64)=0.125 (exact in bf16)
  bf16x8 aq[2];
  const int qrow = q0 + w * 16 + lm;
#pragma unroll
  for (int kk = 0; kk < 2; ++kk) {
    const u16t* src = qkv + (size_t)(b * 2048 + qrow) * 3072 + h * 64 + kk * 32 + lh * 8;
    u16x8 v = *(const u16x8*)src;
    u16x8 o;
#pragma unroll
    for (int e = 0; e < 8; ++e) o[e] = f2bf(bf2f(v[e]) * 0.125f);
    aq[kk] = __builtin_bit_cast(bf16x8, o);
  }

  float mrun = -1e30f;  // running max of row `qrow` (replicated over lh)
  float lsum = 0.f;     // per-lane PARTIAL sum of row `qrow` (this lane's kv slots)
  f32x4 aco[4] = {};    // O[q=lh*4+r][d=nd*16+lm]

  const u16t* Kg = qkv + (size_t)b * 2048 * 3072 + 1024 + h * 64;
  const u16t* Vg = vt + (size_t)bh * 64 * 2048;
  u16t* Pw = &Pl[w][0];

  auto stage = [&](int t) {
#pragma unroll
    for (int s = 0; s < 2; ++s) {
      int c = s * 256 + tid;
      int row = c >> 3, col = ((c & 7) ^ (row & 7)) << 3;
      gload_lds16(Kg + (size_t)(t * 64 + row) * 3072 + col, &Kl[c * 8]);
    }
#pragma unroll
    for (int s = 0; s < 2; ++s) {
      int c = s * 256 + tid;
      int row = c >> 3, col = ((c & 7) ^ (row & 7)) << 3;
      gload_lds16(Vg + (size_t)row * 2048 + t * 64 + col, &Vl[c * 8]);
    }
  };

  for (int t = 0; t < nt; ++t) {
    stage(t);
    asm volatile("s_waitcnt vmcnt(0)" ::: "memory");
    bsync();

    // S^T = K * Q : accs[nk] holds S^T[kv=nk*16+lh*4+r][q=lm]
    f32x4 accs[4] = {};
#pragma unroll
    for (int kk = 0; kk < 2; ++kk) {
      bf16x8 ak[4];
#pragma unroll
      for (int nk = 0; nk < 4; ++nk) {
        int rk = nk * 16 + lm;
        int s16 = (kk * 4 + lh) ^ (rk & 7);
        ak[nk] = ldsfrag(&Kl[rk * 64 + s16 * 8]);
      }
      __builtin_amdgcn_s_setprio(1);
#pragma unroll
      for (int nk = 0; nk < 4; ++nk)
        accs[nk] = __builtin_amdgcn_mfma_f32_16x16x32_bf16(ak[nk], aq[kk],
                                                           accs[nk], 0, 0, 0);
      __builtin_amdgcn_s_setprio(0);
    }

    // per-lane tile max; causal mask only on the diagonal tile (block-uniform)
    float vmax = -1e30f;
    if (t == nt - 1) {
#pragma unroll
      for (int nk = 0; nk < 4; ++nk)
#pragma unroll
        for (int r = 0; r < 4; ++r) {
          int kvpos = t * 64 + nk * 16 + lh * 4 + r;
          float v = accs[nk][r];
          v = (kvpos > qrow) ? -1e30f : v;
          accs[nk][r] = v;
          vmax = fmaxf(vmax, v);
        }
    } else {
#pragma unroll
      for (int nk = 0; nk < 4; ++nk)
#pragma unroll
        for (int r = 0; r < 4; ++r) vmax = fmaxf(vmax, accs[nk][r]);
    }

    // defer-max: rare path only when tile max exceeds running max by >8
    if (!__all(vmax <= mrun + 8.f)) {
      float rm = fmaxf(vmax, __shfl_xor(vmax, 16));
      rm = fmaxf(rm, __shfl_xor(rm, 32));
      float mnew = fmaxf(mrun, rm);
      float alpha = __expf(mrun - mnew);
      mrun = mnew;
      lsum *= alpha;
#pragma unroll
      for (int r = 0; r < 4; ++r) {
        float ar = __shfl(alpha, lh * 4 + r);
#pragma unroll
        for (int nd = 0; nd < 4; ++nd) aco[nd][r] *= ar;
      }
    }

    // p = exp(s - mrun); accumulate partial lsum; pack 4 bf16 -> one b64 LDS write
#pragma unroll
    for (int nk = 0; nk < 4; ++nk) {
      u16x4 pb;
#pragma unroll
      for (int r = 0; r < 4; ++r) {
        float p = __expf(accs[nk][r] - mrun);
        lsum += p;
        pb[r] = f2bf(p);
      }
      int s16 = (nk * 2 + (lh >> 1)) ^ (lm & 7);
      *(u16x4*)&Pw[lm * 64 + s16 * 8 + (lh & 1) * 4] = pb;
    }

    // O += P * V
#pragma unroll
    for (int kk = 0; kk < 2; ++kk) {
      int s16p = (kk * 4 + lh) ^ (lm & 7);
      bf16x8 ap = ldsfrag(&Pw[lm * 64 + s16p * 8]);
      __builtin_amdgcn_s_setprio(1);
#pragma unroll
      for (int nd = 0; nd < 4; ++nd) {
        int rv = nd * 16 + lm;
        int s16v = (kk * 4 + lh) ^ (rv & 7);
        bf16x8 bv = ldsfrag(&Vl[rv * 64 + s16v * 8]);
        aco[nd] = __builtin_amdgcn_mfma_f32_16x16x32_bf16(ap, bv, aco[nd], 0, 0, 0);
      }
      __builtin_amdgcn_s_setprio(0);
    }

    bsync();
  }

  // epilogue: finish lsum reduce, normalize, store
  lsum += __shfl_xor(lsum, 16);
  lsum += __shfl_xor(lsum, 32);
  float inv = 1.0f / lsum;  // for row `qrow` (lane lm)
#pragma unroll
  for (int r = 0; r < 4; ++r) {
    float ir = __shfl(inv, lh * 4 + r);
    int row = q0 + w * 16 + lh * 4 + r;
#pragma unroll
    for (int nd = 0; nd < 4; ++nd) {
      int col = h * 64 + nd * 16 + lm;
      outp[(size_t)(b * 2048 + row) * 1024 + col] = f2bf(aco[nd][r] * ir);
    }
  }
}

extern "C" void kernel_launch(void* const* d_in, const int* in_sizes, int n_in,
                              void* d_out, int out_size, void* d_ws, size_t ws_size,
                              hipStream_t stream) {
  const float* x = (const float*)d_in[0];
  const float* wq = (const float*)d_in[1];
  const float* bq = (const float*)d_in[2];
  const float* wk = (const float*)d_in[3];
  const float* bk = (const float*)d_in[4];
  const float* wv = (const float*)d_in[5];
  const float* bv = (const float*)d_in[6];
  const float* wo = (const float*)d_in[7];
  const float* bo = (const float*)d_in[8];

  char* ws = (char*)d_ws;
  u16t* xb = (u16t*)ws;                    //  8 MB: x bf16 (later reused as attn_out)
  u16t* wqkvT = (u16t*)(ws + (8u << 20));  //  6 MB: [wq^T; wk^T; wv^T] bf16
  u16t* woT = (u16t*)(ws + (14u << 20));   //  2 MB: wo^T bf16
  u16t* qkv = (u16t*)(ws + (16u << 20));   // 24 MB: [4096][3072] bf16 (V third unused)
  u16t* vt = (u16t*)(ws + (40u << 20));    //  8 MB: [32][64][2048] bf16
  u16t* attn_out = xb;

  k_convert_x<<<4096, 256, 0, stream>>>(x, xb);
  k_transw<<<dim3(16, 16, 4), 256, 0, stream>>>(wq, wk, wv, wo, wqkvT, woT);
  k_gemm_bt<true, true><<<dim3(32, 24), 256, 0, stream>>>(xb, wqkvT, qkv, bq, bk,
                                                          bv, vt, 4096, 3072, 1024);
  k_attn<<<dim3(32, 32), 256, 0, stream>>>(qkv, vt, attn_out);
  k_gemm_bt<false, false><<<dim3(32, 8), 256, 0, stream>>>(
      attn_out, woT, d_out, bo, bo, bo, nullptr, 4096, 1024, 1024);
}